// Round 3
// baseline (340.563 us; speedup 1.0000x reference)
//
#include <hip/hip_runtime.h>
#include <hip/hip_bf16.h>
#include <math.h>

typedef float f32x4 __attribute__((ext_vector_type(4)));
typedef short s16x8 __attribute__((ext_vector_type(8)));

__device__ inline short f2bf(float f) {
    union { __hip_bfloat16 h; short s; } u;
    u.h = __float2bfloat16(f);
    return u.s;
}

__device__ inline s16x8 f32x8_to_bf16x8(f32x4 a, f32x4 b) {
    s16x8 o;
    union { __hip_bfloat162 h; short2 s; } u;
    u.h = __float22bfloat162_rn(make_float2(a[0], a[1])); o[0] = u.s.x; o[1] = u.s.y;
    u.h = __float22bfloat162_rn(make_float2(a[2], a[3])); o[2] = u.s.x; o[3] = u.s.y;
    u.h = __float22bfloat162_rn(make_float2(b[0], b[1])); o[4] = u.s.x; o[5] = u.s.y;
    u.h = __float22bfloat162_rn(make_float2(b[2], b[3])); o[6] = u.s.x; o[7] = u.s.y;
    return o;
}

// ---------------------------------------------------------------------------
// Kernel 1: pack weights -> WallT[n][k] bf16, n in [0,384) = f|g|h cols, k in [0,256)
// ---------------------------------------------------------------------------
__global__ __launch_bounds__(256) void wconv_kernel(
    const float* __restrict__ Wf, const float* __restrict__ Wg,
    const float* __restrict__ Wh, short* __restrict__ WallT)
{
    int t = blockIdx.x * 256 + threadIdx.x;   // 0..98303
    int n = t >> 8;
    int k = t & 255;
    float v;
    if (n < 64)       v = Wf[k * 64 + n];
    else if (n < 128) v = Wg[k * 64 + (n - 64)];
    else              v = Wh[k * 256 + (n - 128)];
    WallT[n * 256 + k] = f2bf(v);
}

// ---------------------------------------------------------------------------
// Kernel 2: projections, LDS-free. Grid 1024 x 256 thr; block = 16 pixels.
// The x-fragment A[m=p][k] ALSO serves as B[k][n=p] for GEMM2 (identical
// lane layout), so x is loaded once into registers, no LDS staging.
// Wave w: GEMM1 n-tiles {2w,2w+1}; GEMM2 channels [w*64, w*64+64).
// ---------------------------------------------------------------------------
__global__ __launch_bounds__(256) void proj_kernel(
    const float* __restrict__ x, const short* __restrict__ WallT,
    const float* __restrict__ bfv, const float* __restrict__ bgv,
    const float* __restrict__ bhv,
    short* __restrict__ fg, short* __restrict__ hT)
{
    const int tid  = threadIdx.x;
    const int lane = tid & 63, w = tid >> 6;
    const int quad = lane >> 4, l15 = lane & 15;
    const int p0 = blockIdx.x * 16;

    // x fragment: 64 floats/lane -> bf16
    s16x8 xf[8];
    {
        const float* xrow = x + (size_t)(p0 + l15) * 256 + quad * 8;
        for (int kk = 0; kk < 8; ++kk) {
            f32x4 a = *(const f32x4*)(xrow + kk * 32);
            f32x4 c = *(const f32x4*)(xrow + kk * 32 + 4);
            xf[kk] = f32x8_to_bf16x8(a, c);
        }
    }

    // GEMM1: fg[p][n] = x @ [Wf|Wg] + bias
    for (int i = 0; i < 2; ++i) {
        int nt = w * 2 + i;
        f32x4 acc = {0.f, 0.f, 0.f, 0.f};
        const short* brow = WallT + (nt * 16 + l15) * 256 + quad * 8;
        for (int kk = 0; kk < 8; ++kk) {
            s16x8 bfr = *(const s16x8*)(brow + kk * 32);
            acc = __builtin_amdgcn_mfma_f32_16x16x32_bf16(xf[kk], bfr, acc, 0, 0, 0);
        }
        int n = nt * 16 + l15;
        float bias = (n < 64) ? bfv[n] : bgv[n - 64];
        for (int r = 0; r < 4; ++r) {
            int p = p0 + quad * 4 + r;
            fg[(size_t)p * 128 + n] = f2bf(acc[r] + bias);
        }
    }

    // GEMM2: hT[c][p] = (x @ Wh + bh)^T   (A = WallT rows 128+c, B = xf)
    for (int mt = 0; mt < 4; ++mt) {
        f32x4 acc = {0.f, 0.f, 0.f, 0.f};
        const short* arow = WallT + (size_t)(128 + w * 64 + mt * 16 + l15) * 256 + quad * 8;
        for (int kk = 0; kk < 8; ++kk) {
            s16x8 aa = *(const s16x8*)(arow + kk * 32);
            acc = __builtin_amdgcn_mfma_f32_16x16x32_bf16(aa, xf[kk], acc, 0, 0, 0);
        }
        int p  = p0 + l15;                 // C/D col = l15 = pixel
        int bt = p >> 12, npix = p & 4095;
        for (int r = 0; r < 4; ++r) {
            int c = w * 64 + mt * 16 + quad * 4 + r;
            hT[(size_t)(bt * 256 + c) * 4096 + npix] = f2bf(acc[r] + bhv[c]);
        }
    }
}

// ---------------------------------------------------------------------------
// Kernel 3 (pass 1): softmax stats. Grid 1024 = 4b x 64qt x 4 key-splits,
// 256 thr, NO LDS / barriers. Per-lane online (m,l) over the lane's own key
// columns; one 4-step shuffle combine at the end. Partials in stats[ks][b][q].
// ---------------------------------------------------------------------------
__global__ __launch_bounds__(256) void pass1_kernel(
    const short* __restrict__ fg, float2* __restrict__ stats)
{
    const int tid  = threadIdx.x;
    const int lane = tid & 63, w = tid >> 6;
    const int quad = lane >> 4, l15 = lane & 15;
    const int bx = blockIdx.x;
    const int b  = bx >> 8;
    const int qt = (bx >> 2) & 63;
    const int ks = bx & 3;
    const int q0 = qt * 64;

    const short* qptr = fg + (size_t)(b * 4096 + q0 + w * 16 + l15) * 128 + 64 + quad * 8;
    s16x8 qf0 = *(const s16x8*)(qptr);
    s16x8 qf1 = *(const s16x8*)(qptr + 32);

    float m_l[4] = {-INFINITY, -INFINITY, -INFINITY, -INFINITY};
    float l_l[4] = {0.f, 0.f, 0.f, 0.f};
    const f32x4 zac = {0.f, 0.f, 0.f, 0.f};

    for (int it = 0; it < 16; ++it) {
        int m0 = ks * 1024 + it * 64;
        f32x4 s[4];
        for (int nt = 0; nt < 4; ++nt) {
            const short* kp = fg + (size_t)(b * 4096 + m0 + nt * 16 + l15) * 128 + quad * 8;
            s16x8 kb0 = *(const s16x8*)(kp);
            s16x8 kb1 = *(const s16x8*)(kp + 32);
            f32x4 z = zac;
            z     = __builtin_amdgcn_mfma_f32_16x16x32_bf16(qf0, kb0, z, 0, 0, 0);
            s[nt] = __builtin_amdgcn_mfma_f32_16x16x32_bf16(qf1, kb1, z, 0, 0, 0);
        }
        for (int r = 0; r < 4; ++r) {
            float v0 = s[0][r], v1 = s[1][r], v2 = s[2][r], v3 = s[3][r];
            float mx = fmaxf(fmaxf(v0, v1), fmaxf(v2, v3));
            float mn = fmaxf(m_l[r], mx);
            float alpha = __expf(m_l[r] - mn);     // exp(-inf)=0 on first iter
            l_l[r] = l_l[r] * alpha
                   + (__expf(v0 - mn) + __expf(v1 - mn))
                   + (__expf(v2 - mn) + __expf(v3 - mn));
            m_l[r] = mn;
        }
    }

    // combine across the 16 l15-lanes (keys are striped over l15)
    for (int r = 0; r < 4; ++r) {
        float m = m_l[r], l = l_l[r];
        for (int off = 1; off < 16; off <<= 1) {
            float mo = __shfl_xor(m, off, 64);
            float lo = __shfl_xor(l, off, 64);
            float mn = fmaxf(m, mo);
            l = l * __expf(m - mn) + lo * __expf(mo - mn);
            m = mn;
        }
        if (l15 == 0) {
            int q = q0 + w * 16 + quad * 4 + r;
            stats[((size_t)ks * 4 + b) * 4096 + q] = make_float2(m, l);
        }
    }
}

// ---------------------------------------------------------------------------
// Kernel 4 (pass 2): PV accumulation with known (m, 1/l). Grid 512 = 4b x
// 64qt x 2 channel-halves, 256 thr. Inner loop: QK MFMA (K direct from L2),
// p = exp(s-m)*linv -> P-LDS -> PV MFMA. No shuffles, no rescale, no divide.
// ---------------------------------------------------------------------------
#define VST 72    // Vlds stride: 64 + 8 pad
#define PST 72    // Plds stride

__global__ __launch_bounds__(256) void pass2_kernel(
    const short* __restrict__ fg, const short* __restrict__ hT,
    const float2* __restrict__ stats, const float* __restrict__ xin,
    const float* __restrict__ scale_p, float* __restrict__ out)
{
    __shared__ short Vlds[128 * VST];          // 18.4 KB (channel half)
    __shared__ short Plds[4 * 16 * PST];       //  9.2 KB (per-wave slices)

    const int tid  = threadIdx.x;
    const int lane = tid & 63, w = tid >> 6;
    const int quad = lane >> 4, l15 = lane & 15;
    const int bx  = blockIdx.x;
    const int b   = bx >> 7;
    const int rem = bx & 127;
    const int q0  = (rem >> 1) * 64;
    const int ch0 = (rem & 1) * 128;

    // combine the 4 key-split stat partials -> (m, 1/l) per q-row
    float m_r[4], linv[4];
    for (int r = 0; r < 4; ++r) {
        int q = q0 + w * 16 + quad * 4 + r;
        float m = -INFINITY, l = 0.f;
        for (int ks = 0; ks < 4; ++ks) {
            float2 pr = stats[((size_t)ks * 4 + b) * 4096 + q];
            float mn = fmaxf(m, pr.x);
            l = l * __expf(m - mn) + pr.y * __expf(pr.x - mn);
            m = mn;
        }
        m_r[r] = m;
        linv[r] = 1.f / l;
    }

    // persistent Q A-fragments
    const short* qptr = fg + (size_t)(b * 4096 + q0 + w * 16 + l15) * 128 + 64 + quad * 8;
    s16x8 qf0 = *(const s16x8*)(qptr);
    s16x8 qf1 = *(const s16x8*)(qptr + 32);

    f32x4 oacc[8];
    const f32x4 zac = {0.f, 0.f, 0.f, 0.f};
    for (int ct = 0; ct < 8; ++ct) oacc[ct] = zac;

    const int srow = tid >> 3, sseg = tid & 7;   // V staging: 4 rows/thread
    const short* hsrc = hT + (size_t)(b * 256 + ch0) * 4096;

    for (int m0 = 0; m0 < 4096; m0 += 64) {
        // issue V tile loads early (consumed after softmax -> latency hidden)
        s16x8 vreg[4];
        for (int i = 0; i < 4; ++i)
            vreg[i] = *(const s16x8*)(hsrc + (size_t)(srow + i * 32) * 4096 + m0 + sseg * 8);

        // S = Q K^T  (K fragments direct from global; L2-resident)
        f32x4 s[4];
        for (int nt = 0; nt < 4; ++nt) {
            const short* kp = fg + (size_t)(b * 4096 + m0 + nt * 16 + l15) * 128 + quad * 8;
            s16x8 kb0 = *(const s16x8*)(kp);
            s16x8 kb1 = *(const s16x8*)(kp + 32);
            f32x4 z = zac;
            z     = __builtin_amdgcn_mfma_f32_16x16x32_bf16(qf0, kb0, z, 0, 0, 0);
            s[nt] = __builtin_amdgcn_mfma_f32_16x16x32_bf16(qf1, kb1, z, 0, 0, 0);
        }

        // P = exp(S - m) * (1/l)  -> per-wave Plds slice (C-layout -> A-layout)
        for (int r = 0; r < 4; ++r) {
            float mr = m_r[r], li = linv[r];
            short* prow = Plds + (w * 16 + quad * 4 + r) * PST + l15;
            prow[0]  = f2bf(__expf(s[0][r] - mr) * li);
            prow[16] = f2bf(__expf(s[1][r] - mr) * li);
            prow[32] = f2bf(__expf(s[2][r] - mr) * li);
            prow[48] = f2bf(__expf(s[3][r] - mr) * li);
        }

        // commit V tile to LDS, then cross-wave sync
        for (int i = 0; i < 4; ++i)
            *(s16x8*)(Vlds + (srow + i * 32) * VST + sseg * 8) = vreg[i];
        __syncthreads();

        // O += P V
        const short* pp = Plds + (w * 16 + l15) * PST + quad * 8;
        s16x8 pa0 = *(const s16x8*)(pp);
        s16x8 pa1 = *(const s16x8*)(pp + 32);
        for (int ct = 0; ct < 8; ++ct) {
            const short* vp = Vlds + (ct * 16 + l15) * VST + quad * 8;
            s16x8 vb0 = *(const s16x8*)(vp);
            s16x8 vb1 = *(const s16x8*)(vp + 32);
            oacc[ct] = __builtin_amdgcn_mfma_f32_16x16x32_bf16(pa0, vb0, oacc[ct], 0, 0, 0);
            oacc[ct] = __builtin_amdgcn_mfma_f32_16x16x32_bf16(pa1, vb1, oacc[ct], 0, 0, 0);
        }
        __syncthreads();
    }

    // epilogue: y = scale * O + x   (O already includes 1/l via P)
    const float scale = *scale_p;
    for (int ct = 0; ct < 8; ++ct) {
        for (int r = 0; r < 4; ++r) {
            int p = b * 4096 + q0 + w * 16 + quad * 4 + r;
            size_t idx = (size_t)p * 256 + ch0 + ct * 16 + l15;
            out[idx] = scale * oacc[ct][r] + xin[idx];
        }
    }
}

// ---------------------------------------------------------------------------
extern "C" void kernel_launch(void* const* d_in, const int* in_sizes, int n_in,
                              void* d_out, int out_size, void* d_ws, size_t ws_size,
                              hipStream_t stream) {
    (void)in_sizes; (void)n_in; (void)out_size; (void)ws_size;
    const float* x     = (const float*)d_in[0];
    const float* Wf    = (const float*)d_in[1];
    const float* bfv   = (const float*)d_in[2];
    const float* Wg    = (const float*)d_in[3];
    const float* bgv   = (const float*)d_in[4];
    const float* Wh    = (const float*)d_in[5];
    const float* bhv   = (const float*)d_in[6];
    const float* scale = (const float*)d_in[7];
    float* out = (float*)d_out;

    // workspace layout
    short*  WallT = (short*)d_ws;                         // 384*256
    short*  fg    = WallT + 384 * 256;                    // 16384*128
    short*  hT    = fg + (size_t)16384 * 128;             // 4*256*4096
    float2* stats = (float2*)(hT + (size_t)4 * 256 * 4096);  // [4 ks][4 b][4096]

    wconv_kernel<<<384, 256, 0, stream>>>(Wf, Wg, Wh, WallT);
    proj_kernel<<<1024, 256, 0, stream>>>(x, WallT, bfv, bgv, bhv, fg, hT);
    pass1_kernel<<<1024, 256, 0, stream>>>(fg, stats);
    pass2_kernel<<<512, 256, 0, stream>>>(fg, hT, stats, x, scale, out);
}